// Round 2
// baseline (755.576 us; speedup 1.0000x reference)
//
#include <hip/hip_runtime.h>

#define BB 256
#define TT 512
#define CC 128
#define NR 4   // renormalize every NR steps (exact power-of-2 scaling)

typedef float v2f __attribute__((ext_vector_type(2)));
typedef float v4f __attribute__((ext_vector_type(4)));

// Forward algorithm in the exp domain. One block per batch, ONE wave (64
// threads); lane j owns output columns c0=2j, c1=2j+1. E = exp(transitions)
// lives in per-lane VGPRs as packed row-pairs; alpha is broadcast through LDS
// with no barriers (single-wave, dependence-ordered).
__global__ __launch_bounds__(64, 1)
void crf_forward(const float* __restrict__ em_all,
                 const void* __restrict__ mask,
                 const float* __restrict__ transitions,
                 float* __restrict__ log_den)
{
    const int b = blockIdx.x;
    const int j = threadIdx.x;          // 0..63
    const int c0 = 2 * j;

    __shared__ v4f aL4[CC / 4];         // alpha vector, 128 floats
    v2f* aL2 = (v2f*)aL4;

    // ---- mask dtype detect + per-batch length (mask is prefix-true) ----
    const unsigned char* mb = (const unsigned char*)mask;
    const bool is_u8 = (mb[1] != 0);    // lengths >= 256 so mask[0][1] is set
    int cnt = 0;
    #pragma unroll
    for (int k = 0; k < TT / 64; ++k) {
        const int idx = b * TT + j + k * 64;
        cnt += is_u8 ? (mb[idx] != 0) : (((const int*)mask)[idx] != 0);
    }
    #pragma unroll
    for (int off = 32; off; off >>= 1) cnt += __shfl_xor(cnt, off);
    const int len = cnt;

    // ---- E pairs in VGPRs: Ep0[ii] = (E[2ii][c0], E[2ii+1][c0]), Ep1 col c1
    v2f Ep0[CC / 2], Ep1[CC / 2];
    #pragma unroll
    for (int ii = 0; ii < CC / 2; ++ii) {
        const v2f r0 = *(const v2f*)&transitions[(2 * ii) * CC + c0];
        const v2f r1 = *(const v2f*)&transitions[(2 * ii + 1) * CC + c0];
        Ep0[ii] = v2f{__expf(r0.x), __expf(r1.x)};
        Ep1[ii] = v2f{__expf(r0.y), __expf(r1.y)};
    }
    // Block rematerialization (compiler must keep these in VGPRs or spill,
    // not re-load transitions from global every step).
    #pragma unroll
    for (int ii = 0; ii < CC / 2; ++ii) {
        asm volatile("" : "+v"(Ep0[ii]), "+v"(Ep1[ii]));
    }

    const float* em = em_all + (size_t)b * TT * CC;

    // t = 0 init (exp domain), logoff carries the log scale
    const v2f e00 = *(const v2f*)&em[c0];
    float a0 = __expf(e00.x);
    float a1 = __expf(e00.y);
    float logoff = 0.f;

    // prefetch exp(emissions) for t = 1
    v2f een = {1.f, 1.f};
    if (len > 1) {
        const v2f e = *(const v2f*)&em[CC + c0];
        een = v2f{__expf(e.x), __expf(e.y)};
    }

    for (int t = 1; t < len; ++t) {
        aL2[j] = v2f{a0, a1};           // publish alpha (wave-internal, no barrier)
        const v2f eecur = een;
        if (t + 1 < len) {              // prefetch next step's exp(emit)
            const v2f e = *(const v2f*)&em[(t + 1) * CC + c0];
            een = v2f{__expf(e.x), __expf(e.y)};
        }

        // dot: acc{0,1} = sum_i a_i * E[i][c{0,1}]  (packed-f32 FMAs)
        v2f acc0 = {0.f, 0.f}, acc1 = {0.f, 0.f};
        #pragma unroll
        for (int q = 0; q < CC / 4; ++q) {
            const v4f a4 = aL4[q];      // broadcast read, conflict-free
            const v2f lo = {a4.x, a4.y};
            const v2f hi = {a4.z, a4.w};
            acc0 = __builtin_elementwise_fma(lo, Ep0[2 * q],     acc0);
            acc0 = __builtin_elementwise_fma(hi, Ep0[2 * q + 1], acc0);
            acc1 = __builtin_elementwise_fma(lo, Ep1[2 * q],     acc1);
            acc1 = __builtin_elementwise_fma(hi, Ep1[2 * q + 1], acc1);
        }
        a0 = (acc0.x + acc0.y) * eecur.x;
        a1 = (acc1.x + acc1.y) * eecur.y;

        // periodic renorm: exact power-of-2 scale of wave max
        if ((t & (NR - 1)) == 0) {
            float m = fmaxf(a0, a1);
            #pragma unroll
            for (int off = 32; off; off >>= 1) m = fmaxf(m, __shfl_xor(m, off));
            const int ex = (int)((__float_as_uint(m) >> 23) & 255) - 127;
            const float s = __uint_as_float((unsigned)(127 - ex) << 23); // 2^-ex
            a0 *= s; a1 *= s;
            logoff += (float)ex * 0.6931471805599453f;
        }
    }

    // ---- log_den[b] = logoff + log(sum_j a_j) ----
    float s = a0 + a1;
    #pragma unroll
    for (int off = 32; off; off >>= 1) s += __shfl_xor(s, off);
    if (j == 0) log_den[b] = logoff + __logf(s);
}

__device__ __forceinline__ bool mask_at(const void* mask, bool is_u8, int idx) {
    if (is_u8) return ((const unsigned char*)mask)[idx] != 0;
    return ((const int*)mask)[idx] != 0;
}

// Gold-path score: sum of masked emissions at tags + masked pair transitions.
__global__ __launch_bounds__(256)
void crf_num(const float* __restrict__ em_all,
             const int* __restrict__ tags,
             const void* __restrict__ mask,
             const float* __restrict__ transitions,
             float* __restrict__ log_num)
{
    const int b = blockIdx.x;
    const int j = threadIdx.x;
    const int lane = j & 63;
    const int wid = j >> 6;
    __shared__ float redf[4];

    const unsigned char* mb = (const unsigned char*)mask;
    const bool is_u8 = (mb[1] != 0);

    const float* em = em_all + (size_t)b * TT * CC;
    const int* tg = tags + b * TT;

    float s = 0.f;
    for (int t = j; t < TT; t += 256) {
        if (mask_at(mask, is_u8, b * TT + t)) {
            s += em[t * CC + tg[t]];
            if (t >= 1 && mask_at(mask, is_u8, b * TT + t - 1))
                s += transitions[tg[t - 1] * CC + tg[t]];
        }
    }
    #pragma unroll
    for (int off = 32; off; off >>= 1) s += __shfl_xor(s, off);
    if (lane == 0) redf[wid] = s;
    __syncthreads();
    if (j == 0) log_num[b] = redf[0] + redf[1] + redf[2] + redf[3];
}

__global__ __launch_bounds__(256)
void crf_final(const float* __restrict__ log_den,
               const float* __restrict__ log_num,
               float* __restrict__ out)
{
    const int j = threadIdx.x;   // one thread per batch, B == 256
    const int lane = j & 63;
    const int wid = j >> 6;
    __shared__ float redf[4];
    float v = log_den[j] - log_num[j];
    #pragma unroll
    for (int off = 32; off; off >>= 1) v += __shfl_xor(v, off);
    if (lane == 0) redf[wid] = v;
    __syncthreads();
    if (j == 0) out[0] = (redf[0] + redf[1] + redf[2] + redf[3]) * (1.0f / BB);
}

extern "C" void kernel_launch(void* const* d_in, const int* in_sizes, int n_in,
                              void* d_out, int out_size, void* d_ws, size_t ws_size,
                              hipStream_t stream) {
    const float* emissions   = (const float*)d_in[0];
    const int*   tags        = (const int*)d_in[1];
    const void*  mask        = d_in[2];
    const float* transitions = (const float*)d_in[3];
    float* out = (float*)d_out;

    float* log_den = (float*)d_ws;
    float* log_num = log_den + BB;

    crf_forward<<<BB, 64, 0, stream>>>(emissions, mask, transitions, log_den);
    crf_num<<<BB, 256, 0, stream>>>(emissions, tags, mask, transitions, log_num);
    crf_final<<<1, 256, 0, stream>>>(log_den, log_num, out);
}

// Round 3
// 423.236 us; speedup vs baseline: 1.7852x; 1.7852x over previous
//
#include <hip/hip_runtime.h>

#define BB 256
#define TT 512
#define CC 128

typedef float v2f __attribute__((ext_vector_type(2)));
typedef float v4f __attribute__((ext_vector_type(4)));

__device__ __forceinline__ v2f expv(v2f x) { return v2f{__expf(x.x), __expf(x.y)}; }
__device__ __forceinline__ v2f vlo(v4f x) { return v2f{x.x, x.y}; }
__device__ __forceinline__ v2f vhi(v4f x) { return v2f{x.z, x.w}; }

// Forward algorithm in exp domain. One block per batch, 2 waves (128 thr).
// Lane (h, j): owns output cols c0=2j,c1=2j+1 and input rows [64h, 64h+64).
// E=exp(T) in LDS, per-lane rows, stride 33 v4f slots (528B) so that
// bank-set = (lane + slot) mod 8 -> conflict-free b128 reads with pure
// immediate offsets. Alpha published as duplicated pairs for mov-free pk_fma.
__global__ __launch_bounds__(128, 1)
void crf_forward(const float* __restrict__ em_all,
                 const void* __restrict__ mask,
                 const float* __restrict__ transitions,
                 float* __restrict__ log_den)
{
    const int tid = threadIdx.x;   // 0..127
    const int j   = tid & 63;
    const int h   = tid >> 6;
    const int b   = blockIdx.x;

    __shared__ v4f ETs[128 * 33];  // 67.6 KiB, padded rows
    __shared__ v4f aD[64];         // aD[c] = {a[2c],a[2c],a[2c+1],a[2c+1]}
    __shared__ v2f pbuf[64];       // wave1 partial sums
    __shared__ float hmax1[1];     // wave1 half-max (renorm steps)

    // ---- mask dtype + length (each wave counts the full row independently)
    const unsigned char* mb = (const unsigned char*)mask;
    const bool is_u8 = (mb[1] != 0);   // lengths >= 256 so mask[0][1] is set
    int cnt = 0;
    #pragma unroll
    for (int k = 0; k < TT / 64; ++k) {
        const int idx = b * TT + j + k * 64;
        cnt += is_u8 ? (mb[idx] != 0) : (((const int*)mask)[idx] != 0);
    }
    #pragma unroll
    for (int off = 32; off; off >>= 1) cnt += __shfl_xor(cnt, off);
    const int len = cnt;
    const int lm = (len > 1) ? (len - 1) : 0;

    // ---- init E rows: slot q holds rows i0=64h+2q, i0+1 for cols 2j,2j+1
    v4f* myrow = &ETs[tid * 33];
    #pragma unroll 8
    for (int q = 0; q < 32; ++q) {
        const int i0 = 64 * h + 2 * q;
        const v2f r0 = *(const v2f*)&transitions[i0 * CC + 2 * j];
        const v2f r1 = *(const v2f*)&transitions[(i0 + 1) * CC + 2 * j];
        myrow[q] = v4f{__expf(r0.x), __expf(r0.y), __expf(r1.x), __expf(r1.y)};
    }

    const float* emb = em_all + (size_t)b * TT * CC + 2 * j;
    const v4f* aW = &aD[32 * h];   // this wave's 32 alpha pair-chunks

    v2f a01 = {0.f, 0.f};
    float logoff = 0.f;
    v2f e1 = {0.f, 0.f}, e2 = {0.f, 0.f}, e3 = {0.f, 0.f};
    if (h == 0) {
        a01 = expv(*(const v2f*)&emb[0]);
        aD[j] = v4f{a01.x, a01.x, a01.y, a01.y};
        e1 = expv(*(const v2f*)&emb[(size_t)min(1, lm) * CC]);
        e2 = expv(*(const v2f*)&emb[(size_t)min(2, lm) * CC]);
        e3 = expv(*(const v2f*)&emb[(size_t)min(3, lm) * CC]);
    }
    __syncthreads();

    for (int t = 1; t < len; ++t) {
        // issue next emission load early: its latency hides under the FMA phase
        v2f r3n = {0.f, 0.f};
        if (h == 0) r3n = *(const v2f*)&emb[(size_t)min(t + 3, lm) * CC];

        const bool rn = ((t & 3) == 0);
        float halfmax = 0.f;
        if (rn) {   // uniform within each wave: computed from shared broadcasts
            v4f mx = aW[0];
            #pragma unroll
            for (int q = 1; q < 32; ++q) mx = __builtin_elementwise_max(mx, aW[q]);
            halfmax = fmaxf(fmaxf(mx.x, mx.y), fmaxf(mx.z, mx.w));
            if (h == 1 && j == 0) hmax1[0] = halfmax;
        }

        // matvec partial over this wave's 64 rows (all addresses immediate-offset)
        v2f acc0 = {0.f,0.f}, acc1 = {0.f,0.f}, acc2 = {0.f,0.f}, acc3 = {0.f,0.f};
        #pragma unroll
        for (int q = 0; q < 32; q += 2) {
            const v4f A0 = aW[q];        // broadcast
            const v4f E0 = myrow[q];     // conflict-free spread
            const v4f A1 = aW[q + 1];
            const v4f E1 = myrow[q + 1];
            acc0 = __builtin_elementwise_fma(vlo(A0), vlo(E0), acc0);
            acc1 = __builtin_elementwise_fma(vhi(A0), vhi(E0), acc1);
            acc2 = __builtin_elementwise_fma(vlo(A1), vlo(E1), acc2);
            acc3 = __builtin_elementwise_fma(vhi(A1), vhi(E1), acc3);
        }
        const v2f ps = (acc0 + acc1) + (acc2 + acc3);
        if (h == 1) pbuf[j] = ps;
        __syncthreads();                       // barrier A

        if (h == 0) {
            const v2f ecur = e1;
            e1 = e2; e2 = e3; e3 = expv(r3n);  // shift prefetch pipeline
            v2f tot = ps + pbuf[j];
            a01 = tot * ecur;
            if (rn) {
                const float m = fmaxf(halfmax, hmax1[0]);
                const int ex = (int)((__float_as_uint(m) >> 23) & 255) - 127;
                const float s = __uint_as_float((unsigned)(127 - ex) << 23); // 2^-ex
                a01 *= v2f{s, s};
                logoff += (float)ex * 0.6931471805599453f;
            }
            aD[j] = v4f{a01.x, a01.x, a01.y, a01.y};
        }
        __syncthreads();                       // barrier B
    }

    // ---- log_den[b] = logoff + log(sum over cols) : state lives in wave0
    if (h == 0) {
        float ssum = a01.x + a01.y;
        #pragma unroll
        for (int off = 32; off; off >>= 1) ssum += __shfl_xor(ssum, off);
        if (j == 0) log_den[b] = logoff + __logf(ssum);
    }
}

__device__ __forceinline__ bool mask_at(const void* mask, bool is_u8, int idx) {
    if (is_u8) return ((const unsigned char*)mask)[idx] != 0;
    return ((const int*)mask)[idx] != 0;
}

// Gold-path score: sum of masked emissions at tags + masked pair transitions.
__global__ __launch_bounds__(256)
void crf_num(const float* __restrict__ em_all,
             const int* __restrict__ tags,
             const void* __restrict__ mask,
             const float* __restrict__ transitions,
             float* __restrict__ log_num)
{
    const int b = blockIdx.x;
    const int j = threadIdx.x;
    const int lane = j & 63;
    const int wid = j >> 6;
    __shared__ float redf[4];

    const unsigned char* mb = (const unsigned char*)mask;
    const bool is_u8 = (mb[1] != 0);

    const float* em = em_all + (size_t)b * TT * CC;
    const int* tg = tags + b * TT;

    float s = 0.f;
    for (int t = j; t < TT; t += 256) {
        if (mask_at(mask, is_u8, b * TT + t)) {
            s += em[t * CC + tg[t]];
            if (t >= 1 && mask_at(mask, is_u8, b * TT + t - 1))
                s += transitions[tg[t - 1] * CC + tg[t]];
        }
    }
    #pragma unroll
    for (int off = 32; off; off >>= 1) s += __shfl_xor(s, off);
    if (lane == 0) redf[wid] = s;
    __syncthreads();
    if (j == 0) log_num[b] = redf[0] + redf[1] + redf[2] + redf[3];
}

__global__ __launch_bounds__(256)
void crf_final(const float* __restrict__ log_den,
               const float* __restrict__ log_num,
               float* __restrict__ out)
{
    const int j = threadIdx.x;   // one thread per batch, B == 256
    const int lane = j & 63;
    const int wid = j >> 6;
    __shared__ float redf[4];
    float v = log_den[j] - log_num[j];
    #pragma unroll
    for (int off = 32; off; off >>= 1) v += __shfl_xor(v, off);
    if (lane == 0) redf[wid] = v;
    __syncthreads();
    if (j == 0) out[0] = (redf[0] + redf[1] + redf[2] + redf[3]) * (1.0f / BB);
}

extern "C" void kernel_launch(void* const* d_in, const int* in_sizes, int n_in,
                              void* d_out, int out_size, void* d_ws, size_t ws_size,
                              hipStream_t stream) {
    const float* emissions   = (const float*)d_in[0];
    const int*   tags        = (const int*)d_in[1];
    const void*  mask        = d_in[2];
    const float* transitions = (const float*)d_in[3];
    float* out = (float*)d_out;

    float* log_den = (float*)d_ws;
    float* log_num = log_den + BB;

    crf_forward<<<BB, 128, 0, stream>>>(emissions, mask, transitions, log_den);
    crf_num<<<BB, 256, 0, stream>>>(emissions, tags, mask, transitions, log_num);
    crf_final<<<1, 256, 0, stream>>>(log_den, log_num, out);
}

// Round 4
// 257.315 us; speedup vs baseline: 2.9364x; 1.6448x over previous
//
#include <hip/hip_runtime.h>

#define BB 256
#define TT 512
#define CC 128
#define G  16            // batches per block
#define NBLK (BB / G)    // 16 blocks

typedef short short8 __attribute__((ext_vector_type(8)));
typedef float f32x4  __attribute__((ext_vector_type(4)));

__device__ __forceinline__ unsigned f2bf(float v) {   // f32 -> bf16 bits (RTNE)
    unsigned u = __float_as_uint(v);
    u += 0x7FFFu + ((u >> 16) & 1u);
    return u >> 16;
}
__device__ __forceinline__ unsigned pack2(float a, float b) {
    return f2bf(a) | (f2bf(b) << 16);
}
__device__ __forceinline__ unsigned umx(unsigned a, unsigned b) { return a > b ? a : b; }

// Forward algorithm, exp domain, MFMA. 16 blocks x 4 waves; block handles 16
// batches. E^T is the (static) A-operand held in VGPR fragments; alpha^T is
// the B-operand, bounced through a swizzled 8KB double-buffered LDS tile in
// bf16. Wave w owns output states [32w,32w+32); lane l owns batch n=l&15.
// D layout (verified): col=lane&15 (batch), row=(lane>>4)*4+reg (state) --
// which matches B's col=lane&15, so the per-step relayout is lane-local.
__global__ __launch_bounds__(256, 1)
void crf_forward(const float* __restrict__ em_all,
                 const void* __restrict__ mask,
                 const float* __restrict__ transitions,
                 float* __restrict__ log_den)
{
    const int tid = threadIdx.x;
    const int l = tid & 63, w = tid >> 6;
    const int n = l & 15, g = l >> 4;
    const int bbase = blockIdx.x * G;

    __shared__ __align__(16) unsigned abuf[2][16 * 64];  // bf16 alpha, 2 buffers
    __shared__ float finred[4][16];

    // u32 index of (batch nn, state s): byte = nn*256 + 2*(s ^ ((nn&7)<<4))
    auto aidx = [](int nn, int s) -> int {
        return nn * 64 + ((s ^ ((nn & 7) << 4)) >> 1);
    };

    // ---- mask dtype + per-batch length (prefix-true mask) ----
    const unsigned char* mb = (const unsigned char*)mask;
    const bool is_u8 = (mb[1] != 0);    // lengths >= 256 so mask[0][1] is set
    int cnt = 0;
    const int rowbase = (bbase + n) * TT + g * 128;   // lane counts a quarter-row
    if (is_u8) {
        const uint4* mp = (const uint4*)(mb + rowbase);
        #pragma unroll
        for (int k = 0; k < 8; ++k) {
            const uint4 v = mp[k];
            const unsigned s4 = (v.x & 0x01010101u) + (v.y & 0x01010101u)
                              + (v.z & 0x01010101u) + (v.w & 0x01010101u);
            cnt += (int)((s4 * 0x01010101u) >> 24);
        }
    } else {
        const uint4* mp = (const uint4*)((const unsigned*)mask + rowbase);
        #pragma unroll
        for (int k = 0; k < 32; ++k) {
            const uint4 v = mp[k];
            cnt += (v.x ? 1 : 0) + (v.y ? 1 : 0) + (v.z ? 1 : 0) + (v.w ? 1 : 0);
        }
    }
    cnt += __shfl_xor(cnt, 16); cnt += __shfl_xor(cnt, 32);
    const int len_n = cnt;                 // this lane's batch length
    int lmx = len_n;
    #pragma unroll
    for (int off = 1; off <= 8; off <<= 1) lmx = max(lmx, __shfl_xor(lmx, off));
    const int len_max = lmx;               // uniform loop bound

    // ---- A-fragments: A[m,k] = E^T[m,k] = exp(T[k][m]) ----
    // lane l, elem e of tile (mt,kt): m = 32w+16mt+n, k = 32kt+8g+e
    short8 afr[2][4];
    #pragma unroll
    for (int mt = 0; mt < 2; ++mt) {
        #pragma unroll
        for (int kt = 0; kt < 4; ++kt) {
            short8 a;
            #pragma unroll
            for (int e = 0; e < 8; ++e) {
                const int k = 32 * kt + 8 * g + e;
                const int m = 32 * w + 16 * mt + n;
                a[e] = (short)f2bf(__expf(transitions[k * CC + m]));
            }
            afr[mt][kt] = a;
        }
    }

    // ---- t=0 init: alpha = exp(emissions[:,0,:]) ----
    const float* emb = em_all + (size_t)(bbase + n) * TT * CC;
    const int s0 = 32 * w + 4 * g;         // lane's first state (mt=0); mt=1 at +16
    float av[8]; unsigned pk[4];
    {
        const f32x4 e0 = *(const f32x4*)&emb[s0];
        const f32x4 e1 = *(const f32x4*)&emb[s0 + 16];
        #pragma unroll
        for (int i = 0; i < 4; ++i) { av[i] = __expf(e0[i]); av[4 + i] = __expf(e1[i]); }
        pk[0] = pack2(av[0], av[1]); pk[1] = pack2(av[2], av[3]);
        pk[2] = pack2(av[4], av[5]); pk[3] = pack2(av[6], av[7]);
        *(uint2*)&abuf[0][aidx(n, s0)]      = make_uint2(pk[0], pk[1]);
        *(uint2*)&abuf[0][aidx(n, s0 + 16)] = make_uint2(pk[2], pk[3]);
    }
    // emission prefetch, 2 steps ahead
    f32x4 emc0 = *(const f32x4*)&emb[(size_t)1 * CC + s0];
    f32x4 emc1 = *(const f32x4*)&emb[(size_t)1 * CC + s0 + 16];
    f32x4 emn0 = *(const f32x4*)&emb[(size_t)2 * CC + s0];
    f32x4 emn1 = *(const f32x4*)&emb[(size_t)2 * CC + s0 + 16];
    float logoff = 0.f;

    asm volatile("s_waitcnt lgkmcnt(0)\n\ts_barrier" ::: "memory");

    for (int t = 1; t < len_max; ++t) {
        // prefetch emissions for t+2 (clamped; unused tail is harmless)
        const int tf = (t + 2 < TT) ? (t + 2) : (TT - 1);
        const f32x4 ef0 = *(const f32x4*)&emb[(size_t)tf * CC + s0];
        const f32x4 ef1 = *(const f32x4*)&emb[(size_t)tf * CC + s0 + 16];

        // B-fragments: alpha^T[k, n], k = 32kt+8g+e, from buf[(t+1)&1]
        const unsigned* rbuf = abuf[(t + 1) & 1];
        uint4 rbu[4];
        #pragma unroll
        for (int kt = 0; kt < 4; ++kt)
            rbu[kt] = *(const uint4*)&rbuf[aidx(n, 32 * kt + 8 * g)];

        f32x4 acc0 = {0.f, 0.f, 0.f, 0.f}, acc1 = {0.f, 0.f, 0.f, 0.f};
        #pragma unroll
        for (int kt = 0; kt < 4; ++kt) {
            const short8 bf = __builtin_bit_cast(short8, rbu[kt]);
            acc0 = __builtin_amdgcn_mfma_f32_16x16x32_bf16(afr[0][kt], bf, acc0, 0, 0, 0);
            acc1 = __builtin_amdgcn_mfma_f32_16x16x32_bf16(afr[1][kt], bf, acc1, 0, 0, 0);
        }

        // renorm every 4 steps: per-batch max of the bf16 alpha just read
        // (identical data in all waves -> identical exact power-of-2 scale)
        int ex = 0; float scale = 1.0f;
        if ((t & 3) == 0) {
            unsigned mx = 0;
            #pragma unroll
            for (int kt = 0; kt < 4; ++kt) {
                mx = umx(mx, rbu[kt].x & 0xFFFF0000u); mx = umx(mx, rbu[kt].x << 16);
                mx = umx(mx, rbu[kt].y & 0xFFFF0000u); mx = umx(mx, rbu[kt].y << 16);
                mx = umx(mx, rbu[kt].z & 0xFFFF0000u); mx = umx(mx, rbu[kt].z << 16);
                mx = umx(mx, rbu[kt].w & 0xFFFF0000u); mx = umx(mx, rbu[kt].w << 16);
            }
            mx = umx(mx, (unsigned)__shfl_xor((int)mx, 16));
            mx = umx(mx, (unsigned)__shfl_xor((int)mx, 32));
            ex = (int)((mx >> 23) & 255u) - 127;
            scale = __uint_as_float((unsigned)(127 - ex) << 23);   // 2^-ex
        }

        const bool active = (t < len_n);
        float nv[8];
        #pragma unroll
        for (int i = 0; i < 4; ++i) {
            nv[i]     = acc0[i] * __expf(emc0[i]) * scale;
            nv[4 + i] = acc1[i] * __expf(emc1[i]) * scale;
        }
        if (active) {
            #pragma unroll
            for (int i = 0; i < 8; ++i) av[i] = nv[i];
            pk[0] = pack2(av[0], av[1]); pk[1] = pack2(av[2], av[3]);
            pk[2] = pack2(av[4], av[5]); pk[3] = pack2(av[6], av[7]);
            logoff += (float)ex * 0.69314718f;
        }
        emc0 = emn0; emc1 = emn1; emn0 = ef0; emn1 = ef1;

        // publish alpha for t+1 (frozen lanes rewrite their held value)
        unsigned* wbuf = abuf[t & 1];
        *(uint2*)&wbuf[aidx(n, s0)]      = make_uint2(pk[0], pk[1]);
        *(uint2*)&wbuf[aidx(n, s0 + 16)] = make_uint2(pk[2], pk[3]);

        asm volatile("s_waitcnt lgkmcnt(0)\n\ts_barrier" ::: "memory");
    }

    // ---- log_den[b] = logoff + log(sum over states) ----
    float s = ((av[0] + av[1]) + (av[2] + av[3])) + ((av[4] + av[5]) + (av[6] + av[7]));
    s += __shfl_xor(s, 16); s += __shfl_xor(s, 32);   // over g within wave
    if (l < 16) finred[w][l] = s;                     // l==n here
    __syncthreads();
    if (w == 0 && l < 16) {
        const float tot = finred[0][l] + finred[1][l] + finred[2][l] + finred[3][l];
        log_den[bbase + l] = logoff + __logf(tot);
    }
}

__device__ __forceinline__ bool mask_at(const void* mask, bool is_u8, int idx) {
    if (is_u8) return ((const unsigned char*)mask)[idx] != 0;
    return ((const int*)mask)[idx] != 0;
}

// Gold-path score: sum of masked emissions at tags + masked pair transitions.
__global__ __launch_bounds__(256)
void crf_num(const float* __restrict__ em_all,
             const int* __restrict__ tags,
             const void* __restrict__ mask,
             const float* __restrict__ transitions,
             float* __restrict__ log_num)
{
    const int b = blockIdx.x;
    const int j = threadIdx.x;
    const int lane = j & 63;
    const int wid = j >> 6;
    __shared__ float redf[4];

    const unsigned char* mb = (const unsigned char*)mask;
    const bool is_u8 = (mb[1] != 0);

    const float* em = em_all + (size_t)b * TT * CC;
    const int* tg = tags + b * TT;

    float s = 0.f;
    for (int t = j; t < TT; t += 256) {
        if (mask_at(mask, is_u8, b * TT + t)) {
            s += em[t * CC + tg[t]];
            if (t >= 1 && mask_at(mask, is_u8, b * TT + t - 1))
                s += transitions[tg[t - 1] * CC + tg[t]];
        }
    }
    #pragma unroll
    for (int off = 32; off; off >>= 1) s += __shfl_xor(s, off);
    if (lane == 0) redf[wid] = s;
    __syncthreads();
    if (j == 0) log_num[b] = redf[0] + redf[1] + redf[2] + redf[3];
}

__global__ __launch_bounds__(256)
void crf_final(const float* __restrict__ log_den,
               const float* __restrict__ log_num,
               float* __restrict__ out)
{
    const int j = threadIdx.x;   // one thread per batch, B == 256
    const int lane = j & 63;
    const int wid = j >> 6;
    __shared__ float redf[4];
    float v = log_den[j] - log_num[j];
    #pragma unroll
    for (int off = 32; off; off >>= 1) v += __shfl_xor(v, off);
    if (lane == 0) redf[wid] = v;
    __syncthreads();
    if (j == 0) out[0] = (redf[0] + redf[1] + redf[2] + redf[3]) * (1.0f / BB);
}

extern "C" void kernel_launch(void* const* d_in, const int* in_sizes, int n_in,
                              void* d_out, int out_size, void* d_ws, size_t ws_size,
                              hipStream_t stream) {
    const float* emissions   = (const float*)d_in[0];
    const int*   tags        = (const int*)d_in[1];
    const void*  mask        = d_in[2];
    const float* transitions = (const float*)d_in[3];
    float* out = (float*)d_out;

    float* log_den = (float*)d_ws;
    float* log_num = log_den + BB;

    crf_forward<<<NBLK, 256, 0, stream>>>(emissions, mask, transitions, log_den);
    crf_num<<<BB, 256, 0, stream>>>(emissions, tags, mask, transitions, log_num);
    crf_final<<<1, 256, 0, stream>>>(log_den, log_num, out);
}